// Round 14
// baseline (296.246 us; speedup 1.0000x reference)
//
#include <hip/hip_runtime.h>
#include <stdint.h>
#include <math.h>

#define B_   16
#define T_   50
#define C_   200
#define N_   10000      // T_*C_
#define NT_  160000     // B_*N_
#define H_   8
#define E_   5120000
#define EPS_ 1e-5f
#define NB_  625        // CSR buckets: dst>>8
#define EB_  512        // edge blocks for hist/append
#define EPB_ 10000      // edges per block (E_/EB_)
#define ATH_ 1024       // threads for hist/append
#define GB_  16         // chunks per graph (gat) -> grid = 256 = 1 block/CU
#define GC_  625        // nodes per chunk (N_/GB_)
#define GTH_ 640        // threads for gat (10 waves, 625 active in edge loop)
#define ECAP_ 24576     // per-block LDS edge staging (mean 20000, +32 sigma)
#define JC_  5          // column chunks per perm tile
#define JW_  40         // columns per chunk
#define ROWP_ 41        // padded LDS row stride
#define BCAP_ 10240     // k_bcsr LDS staging capacity
#define LOG2E_ 1.44269504088896340736f

// native single-instruction transcendentals
__device__ __forceinline__ float ex2(float x){
  float r; asm("v_exp_f32 %0, %1" : "=v"(r) : "v"(x)); return r;
}
// exp2(-|x|) in ONE instruction via VOP3 input modifiers
__device__ __forceinline__ float ex2na(float x){
  float r; asm("v_exp_f32 %0, -abs(%1)" : "=v"(r) : "v"(x)); return r;
}
__device__ __forceinline__ float lg2(float x){
  float r; asm("v_log_f32 %0, %1" : "=v"(r) : "v"(x)); return r;
}

// wave-64 inclusive scan (shfl)
__device__ __forceinline__ int wscan_incl(int v, int lane){
#pragma unroll
  for (int d = 1; d < 64; d <<= 1){
    int t = __shfl_up(v, d, 64);
    if (lane >= d) v += t;
  }
  return v;
}

// ---------------- Threefry-2x32 (JAX) ----------------
struct TF2C { unsigned a, b; };
constexpr unsigned rotl32c(unsigned v, int r){ return (v << r) | (v >> (32 - r)); }
constexpr TF2C tf_const(unsigned k0, unsigned k1, unsigned x0, unsigned x1){
  unsigned ks2 = k0 ^ k1 ^ 0x1BD11BDAu;
  unsigned ks[3] = {k0, k1, ks2};
  x0 += k0; x1 += k1;
  const int RA[4] = {13, 15, 26, 6};
  const int RB[4] = {17, 29, 16, 24};
  for (int g = 0; g < 5; ++g){
    for (int r = 0; r < 4; ++r){
      int rr = (g & 1) ? RB[r] : RA[r];
      x0 += x1; x1 = rotl32c(x1, rr); x1 ^= x0;
    }
    x0 += ks[(g + 1) % 3];
    x1 += ks[(g + 2) % 3] + (unsigned)(g + 1);
  }
  return TF2C{x0, x1};
}
constexpr TF2C KG = tf_const(0u, 42u, 0u, 0u);
constexpr TF2C KN = tf_const(0u, 42u, 0u, 1u);

#define ROTL_(x, r) __builtin_amdgcn_alignbit((x), (x), 32 - (r))

__device__ __forceinline__ void tf2(unsigned k0, unsigned k1, unsigned x0, unsigned x1,
                                    unsigned &o0, unsigned &o1){
  unsigned ks2 = k0 ^ k1 ^ 0x1BD11BDAu;
  x0 += k0; x1 += k1;
#define TFR_(R) { x0 += x1; x1 = ROTL_(x1, R); x1 ^= x0; }
  TFR_(13) TFR_(15) TFR_(26) TFR_(6)  x0 += k1;  x1 += ks2 + 1u;
  TFR_(17) TFR_(29) TFR_(16) TFR_(24) x0 += ks2; x1 += k0 + 2u;
  TFR_(13) TFR_(15) TFR_(26) TFR_(6)  x0 += k0;  x1 += k1 + 3u;
  TFR_(17) TFR_(29) TFR_(16) TFR_(24) x0 += k1;  x1 += ks2 + 4u;
  TFR_(13) TFR_(15) TFR_(26) TFR_(6)  x0 += ks2; x1 += k0 + 5u;
#undef TFR_
  o0 = x0; o1 = x1;
}
__device__ __forceinline__ unsigned rbits(unsigned ka, unsigned kb, unsigned m){
  unsigned a, b; tf2(ka, kb, 0u, m, a, b); return a ^ b;
}

__device__ __forceinline__ float erfinv_xla(float x){
  float w = -log1pf(-x * x);
  float p;
  if (w < 5.0f){
    w = w - 2.5f;
    p = 2.81022636e-08f;
    p = fmaf(p, w, 3.43273939e-07f);
    p = fmaf(p, w, -3.5233877e-06f);
    p = fmaf(p, w, -4.39150654e-06f);
    p = fmaf(p, w, 0.00021858087f);
    p = fmaf(p, w, -0.00125372503f);
    p = fmaf(p, w, -0.00417768164f);
    p = fmaf(p, w, 0.246640727f);
    p = fmaf(p, w, 1.50140941f);
  } else {
    w = sqrtf(w) - 3.0f;
    p = -0.000200214257f;
    p = fmaf(p, w, 0.000100950558f);
    p = fmaf(p, w, 0.00134934322f);
    p = fmaf(p, w, -0.00367342844f);
    p = fmaf(p, w, 0.00573950773f);
    p = fmaf(p, w, -0.0076224613f);
    p = fmaf(p, w, 0.00943887047f);
    p = fmaf(p, w, 1.00167406f);
    p = fmaf(p, w, 2.83297682f);
  }
  return p * x;
}

// ---------------- CSR build ----------------
__global__ __launch_bounds__(ATH_)
void k_hist(const int* __restrict__ dst, int* __restrict__ cnt){
  __shared__ int h[NB_];
  int tid = threadIdx.x, blk = blockIdx.x;
  for (int i = tid; i < NB_; i += ATH_) h[i] = 0;
  __syncthreads();
  int e0 = blk * EPB_;
  for (int i = tid; i < EPB_; i += ATH_)
    atomicAdd(&h[dst[e0 + i] >> 8], 1);
  __syncthreads();
  for (int i = tid; i < NB_; i += ATH_) cnt[blk * NB_ + i] = h[i];
}

__global__ __launch_bounds__(512)
void k_sumb(const int* __restrict__ cnt, int* __restrict__ bsum){
  __shared__ int sred[8];
  int b = blockIdx.x, tid = threadIdx.x;
  int v = cnt[tid * NB_ + b];
#pragma unroll
  for (int s = 32; s >= 1; s >>= 1) v += __shfl_xor(v, s, 64);
  int w = tid >> 6, l = tid & 63;
  if (l == 0) sred[w] = v;
  __syncthreads();
  if (tid == 0){
    int t = 0;
#pragma unroll
    for (int i = 0; i < 8; ++i) t += sred[i];
    bsum[b] = t;
  }
}

__global__ __launch_bounds__(640)
void k_scanb(const int* __restrict__ bsum, int* __restrict__ boff){
  __shared__ int wsum[16];
  int tid = threadIdx.x, lane = tid & 63, wid = tid >> 6;   // 10 waves
  int v = (tid < NB_) ? bsum[tid] : 0;
  int inc = wscan_incl(v, lane);
  if (lane == 63) wsum[wid] = inc;
  __syncthreads();
  if (wid == 0){
    int wv = (lane < 10) ? wsum[lane] : 0;
    int wi = wscan_incl(wv, lane);
    if (lane < 10) wsum[lane] = wi - wv;
  }
  __syncthreads();
  if (tid < NB_) boff[tid] = inc - v + wsum[wid];
  if (tid == 0) boff[NB_] = E_;
}

__global__ __launch_bounds__(512)
void k_scanc(const int* __restrict__ cnt, const int* __restrict__ boff,
             int* __restrict__ gscan){
  __shared__ int wsum[8];
  int b = blockIdx.x, tid = threadIdx.x, lane = tid & 63, wid = tid >> 6;
  int v = cnt[tid * NB_ + b];
  int inc = wscan_incl(v, lane);
  if (lane == 63) wsum[wid] = inc;
  __syncthreads();
  int wp = 0;
#pragma unroll
  for (int k = 0; k < 8; ++k) wp += (k < wid) ? wsum[k] : 0;
  gscan[tid * NB_ + b] = boff[b] + inc - v + wp;
}

__global__ __launch_bounds__(ATH_)
void k_append(const int* __restrict__ src, const int* __restrict__ dst,
              const int* __restrict__ cnt, const int* __restrict__ gscan,
              unsigned* __restrict__ ebuf){
  __shared__ unsigned esh[EPB_];     // 40 KB staging
  __shared__ int loff[NB_ + 1];
  __shared__ int cur[NB_];
  __shared__ int wsum[16];
  int tid = threadIdx.x, blk = blockIdx.x;
  int lane = tid & 63, wid = tid >> 6;
  int e0 = blk * EPB_;
  for (int i = tid; i < NB_; i += ATH_) cur[i] = 0;
  int hv = (tid < NB_) ? cnt[blk * NB_ + tid] : 0;
  int inc = wscan_incl(hv, lane);
  if (lane == 63 && wid < 10) wsum[wid] = inc;
  __syncthreads();
  if (wid == 0){
    int wv = (lane < 10) ? wsum[lane] : 0;
    int wi = wscan_incl(wv, lane);
    if (lane < 10) wsum[lane] = wi - wv;
  }
  __syncthreads();
  if (tid < NB_) loff[tid] = inc - hv + wsum[wid];
  if (tid == 0) loff[NB_] = EPB_;
  __syncthreads();
  for (int i = tid; i < EPB_; i += ATH_){
    int e = e0 + i;
    int d = dst[e];
    int b = d >> 8;
    int p = loff[b] + atomicAdd(&cur[b], 1);
    esh[p] = ((unsigned)src[e] << 8) | (unsigned)(d & 255);
  }
  __syncthreads();
  for (int b = wid; b < NB_; b += ATH_ / 64){
    int lo = loff[b], len = loff[b + 1] - lo;
    int gb0 = gscan[blk * NB_ + b];
    for (int p = lane; p < len; p += 64)
      ebuf[gb0 + p] = esh[lo + p];
  }
}

__global__ __launch_bounds__(512)
void k_bcsr(const int* __restrict__ boff, const unsigned* __restrict__ ebuf,
            int* __restrict__ offs, unsigned short* __restrict__ srcs16){
  __shared__ unsigned esh[BCAP_];    // 40 KB
  __shared__ int cnt[256];
  __shared__ int cur[256];
  __shared__ int wsum[4];
  int b = blockIdx.x, tid = threadIdx.x, lane = tid & 63, wid = tid >> 6;
  int e0 = boff[b], e1 = boff[b + 1];
  int len = e1 - e0;
  int base_node = b * 256;
  int offA = (base_node / N_) * N_;
  int boundary = offA + N_;
  bool staged = (len <= BCAP_);
  if (tid < 256) cnt[tid] = 0;
  __syncthreads();
  if (staged){
    for (int e = tid; e < len; e += 512){
      unsigned pk = ebuf[e0 + e];
      esh[e] = pk;
      atomicAdd(&cnt[pk & 255u], 1);
    }
  } else {
    for (int e = tid; e < len; e += 512)
      atomicAdd(&cnt[ebuf[e0 + e] & 255u], 1);
  }
  __syncthreads();
  int v = (tid < 256) ? cnt[tid] : 0;
  int inc = wscan_incl(v, lane);
  if (lane == 63 && wid < 4) wsum[wid] = inc;
  __syncthreads();
  int wp = 0;
#pragma unroll
  for (int k = 0; k < 4; ++k) wp += (k < wid) ? wsum[k] : 0;
  int excl = inc - v + wp;
  if (tid < 256){ offs[base_node + tid] = e0 + excl; cur[tid] = excl; }
  __syncthreads();
  if (staged){
    for (int e = tid; e < len; e += 512){
      unsigned pk = esh[e];
      int dl = (int)(pk & 255u);
      int goff = (base_node + dl >= boundary) ? boundary : offA;
      int pos = e0 + atomicAdd(&cur[dl], 1);
      srcs16[pos] = (unsigned short)((int)(pk >> 8) - goff);
    }
  } else {
    for (int e = tid; e < len; e += 512){
      unsigned pk = ebuf[e0 + e];
      int dl = (int)(pk & 255u);
      int goff = (base_node + dl >= boundary) ? boundary : offA;
      int pos = e0 + atomicAdd(&cur[dl], 1);
      srcs16[pos] = (unsigned short)((int)(pk >> 8) - goff);
    }
  }
  if (b == 0 && tid == 0) offs[NT_] = E_;
}

// ---------------- permutation layer ----------------
__global__ __launch_bounds__(512, 8)
void k_perm(const float* __restrict__ W, const float* __restrict__ x,
            float* __restrict__ ypart){
  __shared__ float ez[C_ * ROWP_];          // 32.8 KB
  __shared__ float Ssh[JW_];
  __shared__ float rs[JW_];

  const int bid = blockIdx.x;               // tb*JC_ + jc
  const int tb = bid / JC_;
  const int jc = bid - tb * JC_;
  const int t = tb / B_;
  const int b = tb - t * B_;
  const int j0 = jc * JW_;
  const int xoff = (b * T_ + t) * C_;
  const int tid = threadIdx.x;
  const int w = tid >> 6, l = tid & 63;

  {
    int i  = tid / 10;                       // quad row (10 quads per row)
    int jq = tid - i * 10;                   // quad col
    unsigned m = (unsigned)(tb * (C_ * C_) + i * C_ + j0 + 4 * jq);
    int la = i * ROWP_ + 4 * jq;
    int niter = (2000 - tid + 511) >> 9;     // 3 or 4 quads per thread
    for (int it = 0; it < niter; ++it){
      float4 w4 = *reinterpret_cast<const float4*>(W + m);   // m % 4 == 0
      unsigned bb0 = rbits(KG.a, KG.b, m);
      unsigned bb1 = rbits(KG.a, KG.b, m + 1u);
      unsigned bb2 = rbits(KG.a, KG.b, m + 2u);
      unsigned bb3 = rbits(KG.a, KG.b, m + 3u);
      unsigned bbv[4] = {bb0, bb1, bb2, bb3};
      float wvv[4] = {w4.x, w4.y, w4.z, w4.w};
#pragma unroll
      for (int k = 0; k < 4; ++k){
        unsigned bits = bbv[k];
        float fc = (float)(bits >> 9);                 // exact, = f * 2^23
        float u  = fmaf(fc, 0x1p-23f, 1e-10f);         // uniform(1e-10,1)
        float tl = lg2(u) * -0.69314718056f;           // -ln(u)
        float d  = fmaf(-fc, 0x1p-23f, 1.0f);          // exact 1-f
        float p  = 0.25f;                              // -log(1-d) = d*poly(d)
        p = fmaf(p, d, 0.33333333f);
        p = fmaf(p, d, 0.5f);
        p = fmaf(p, d, 1.0f);
        float tneg = (bits >= 0xFC000000u) ? d * p : tl;   // f >= 1-2^-6 -> poly
        ez[la + k] = ex2(wvv[k] * LOG2E_) * __builtin_amdgcn_rcpf(tneg);
      }
      jq += 2;
      int wrap = jq >= 10;
      jq = wrap ? jq - 10 : jq;
      m  += wrap ? 10368u : 10208u;
      la += wrap ? 2100 : 2099;
    }
  }
  __syncthreads();

#pragma unroll
  for (int q = 0; q < 5; ++q){
    int jj = w * 5 + q;
    float s = ez[l * ROWP_ + jj] + ez[(l + 64) * ROWP_ + jj] + ez[(l + 128) * ROWP_ + jj]
            + ((l < 8) ? ez[(l + 192) * ROWP_ + jj] : 0.f);
#pragma unroll
    for (int sh = 32; sh >= 1; sh >>= 1) s += __shfl_xor(s, sh, 64);
    if (l == 0) Ssh[jj] = s;
  }
  __syncthreads();
  if (tid < JW_) rs[tid] = x[xoff + j0 + tid] / Ssh[tid];
  __syncthreads();

  if (tid < C_){
    float acc = 0.f;
#pragma unroll 8
    for (int jj = 0; jj < JW_; ++jj)
      acc = fmaf(ez[tid * ROWP_ + jj], rs[jj], acc);
    ypart[jc * NT_ + xoff + tid] = acc;
  }
}

// combine 5 column-chunk partials -> y, plus nonzero stats partials
__global__ __launch_bounds__(256)
void k_ycomb(const float* __restrict__ ypart, float* __restrict__ y,
             float* __restrict__ spart){
  __shared__ float sred[12];
  int n = blockIdx.x * 256 + threadIdx.x;
  float v = 0.f;
#pragma unroll
  for (int jc = 0; jc < JC_; ++jc) v += ypart[jc * NT_ + n];
  y[n] = v;
  float s = 0.f, c = 0.f, q = 0.f;
  if (v != 0.f){ s = v; c = 1.f; q = v * v; }
#pragma unroll
  for (int sh = 32; sh >= 1; sh >>= 1){
    s += __shfl_xor(s, sh, 64);
    c += __shfl_xor(c, sh, 64);
    q += __shfl_xor(q, sh, 64);
  }
  int w = threadIdx.x >> 6, l = threadIdx.x & 63;
  if (l == 0){ sred[w] = s; sred[4 + w] = c; sred[8 + w] = q; }
  __syncthreads();
  if (threadIdx.x == 0){
    spart[blockIdx.x * 3 + 0] = sred[0] + sred[1] + sred[2] + sred[3];
    spart[blockIdx.x * 3 + 1] = sred[4] + sred[5] + sred[6] + sred[7];
    spart[blockIdx.x * 3 + 2] = sred[8] + sred[9] + sred[10] + sred[11];
  }
}

__global__ void k_stat2(const float* __restrict__ spart, float* __restrict__ stats){
  __shared__ float sred[12];
  int tid = threadIdx.x;
  float s = 0.f, c = 0.f, q = 0.f;
  for (int i = tid; i < 625; i += 256){
    s += spart[i * 3 + 0];
    c += spart[i * 3 + 1];
    q += spart[i * 3 + 2];
  }
#pragma unroll
  for (int sh = 32; sh >= 1; sh >>= 1){
    s += __shfl_xor(s, sh, 64);
    c += __shfl_xor(c, sh, 64);
    q += __shfl_xor(q, sh, 64);
  }
  int w = tid >> 6, l = tid & 63;
  if (l == 0){ sred[w] = s; sred[4 + w] = c; sred[8 + w] = q; }
  __syncthreads();
  if (tid == 0){
    float S = sred[0] + sred[1] + sred[2] + sred[3];
    float C = sred[4] + sred[5] + sred[6] + sred[7];
    float Q = sred[8] + sred[9] + sred[10] + sred[11];
    float var = (Q - S * S / C) / (C - 1.f);
    stats[0] = sqrtf(var) * 0.01f;
  }
}

// ---------------- fused GAT pass ----------------
// MODE 0: normal.  MODE 1: inline noise injection during staging (pass 1).
// MODE 2: fused mask + global-max-pool output, no xout write (pass 4).
// Block's 625 contiguous nodes own a CONTIGUOUS srcs16 range -> stage it in
// LDS (coalesced once) so the per-lane edge streams become LDS reads.
template<int MODE>
__global__ __launch_bounds__(GTH_)
void k_gat(const float* __restrict__ xin, const float* __restrict__ xres,
           const int* __restrict__ offs, const unsigned short* __restrict__ srcs16,
           const float* __restrict__ gw, const float* __restrict__ asrc,
           const float* __restrict__ adst, const float* __restrict__ gbias,
           const float* __restrict__ bng, const float* __restrict__ bnb,
           const float* __restrict__ bnm, const float* __restrict__ bnv,
           const float* __restrict__ stats, const float* __restrict__ dv,
           float* __restrict__ xout, float* __restrict__ pmax){
  __shared__ float xsh[N_];                      // whole graph: 40 KB
  __shared__ unsigned short eshE[ECAP_];         // edge staging: 48 KB
  __shared__ float sred[10];
  int g = blockIdx.x / GB_, c = blockIdx.x - g * GB_;
  int tid = threadIdx.x;
  if (MODE == 1){
    float scale = stats[0];
    for (int i = tid; i < N_; i += GTH_){
      float v = xin[g * N_ + i];
      if (v == 0.0f){
        unsigned bits = rbits(KN.a, KN.b, (unsigned)(g * N_ + i));
        float f = __uint_as_float((bits >> 9) | 0x3f800000u) - 1.0f;
        float u = fmaf(f, 2.0f, -0.99999994f);
        u = fmaxf(-0.99999994f, u);
        v = scale * 1.41421356237f * erfinv_xla(u);
      }
      xsh[i] = v;
    }
  } else {
    const float4* xv = (const float4*)(xin + g * N_);
    for (int i = tid; i < N_ / 4; i += GTH_) ((float4*)xsh)[i] = xv[i];
  }
  int nbase = g * N_ + c * GC_;
  int eblo = offs[nbase];
  int ebhi = offs[nbase + GC_];
  int eblen = ebhi - eblo;
  bool use_lds = (eblen <= ECAP_);
  if (use_lds)
    for (int i = tid; i < eblen; i += GTH_) eshE[i] = srcs16[eblo + i];
  __syncthreads();

  bool act = tid < GC_;
  int nl = c * GC_ + (act ? tid : 0);
  int n = g * N_ + nl;
  float xn = xsh[nl];

  float cs[H_], cdxn[H_], wv[H_];
#pragma unroll
  for (int h = 0; h < H_; ++h){
    wv[h] = gw[h];
    cs[h] = wv[h] * asrc[h] * LOG2E_;
    cdxn[h] = wv[h] * adst[h] * xn * LOG2E_;
  }
  float mh[H_], den[H_], num[H_];
#pragma unroll
  for (int h = 0; h < H_; ++h){
    float v = cs[h] * xn + cdxn[h];
    v = fmaxf(v, 0.2f * v);
    mh[h] = v; den[h] = 1.f; num[h] = xn;
  }
  int e0 = offs[n], e1 = act ? offs[n + 1] : e0;

  if (use_lds){
    int le = e0 - eblo, le1 = e1 - eblo;
    if ((le < le1) && (le & 1)){            // peel to align pair loads
      float xs = xsh[eshE[le]];
#pragma unroll
      for (int h = 0; h < H_; ++h){
        float v = fmaf(cs[h], xs, cdxn[h]);
        v = fmaxf(v, 0.2f * v);
        float d = v - mh[h];
        float ed = ex2na(d);
        bool nm = d > 0.f;
        float corr = nm ? ed : 1.f;
        float p    = nm ? 1.f : ed;
        mh[h] = fmaxf(mh[h], v);
        den[h] = fmaf(den[h], corr, p);
        num[h] = fmaf(num[h], corr, p * xs);
      }
      ++le;
    }
    for (; le + 1 < le1; le += 2){
      unsigned pr = *reinterpret_cast<const unsigned*>(eshE + le);  // aligned
      float xa = xsh[pr & 0xFFFFu];
      float xb = xsh[pr >> 16];
#pragma unroll
      for (int h = 0; h < H_; ++h){
        float va = fmaf(cs[h], xa, cdxn[h]);  va = fmaxf(va, 0.2f * va);
        float vb = fmaf(cs[h], xb, cdxn[h]);  vb = fmaxf(vb, 0.2f * vb);
        float m2 = fmaxf(va, vb);
        float ed2 = ex2na(va - vb);
        bool bmx = vb > va;
        float xmx = bmx ? xb : xa;
        float xmn = bmx ? xa : xb;
        float den2 = 1.0f + ed2;
        float num2 = fmaf(ed2, xmn, xmx);
        float d = m2 - mh[h];
        float ed = ex2na(d);
        bool nm = d > 0.f;
        float corr = nm ? ed : 1.f;
        float p    = nm ? 1.f : ed;
        mh[h] = fmaxf(mh[h], m2);
        den[h] = fmaf(den[h], corr, p * den2);
        num[h] = fmaf(num[h], corr, p * num2);
      }
    }
    if (le < le1){                          // tail edge
      float xs = xsh[eshE[le]];
#pragma unroll
      for (int h = 0; h < H_; ++h){
        float v = fmaf(cs[h], xs, cdxn[h]);
        v = fmaxf(v, 0.2f * v);
        float d = v - mh[h];
        float ed = ex2na(d);
        bool nm = d > 0.f;
        float corr = nm ? ed : 1.f;
        float p    = nm ? 1.f : ed;
        mh[h] = fmaxf(mh[h], v);
        den[h] = fmaf(den[h], corr, p);
        num[h] = fmaf(num[h], corr, p * xs);
      }
    }
  } else {                                  // fallback (statistically never)
    for (int e = e0; e < e1; ++e){
      float xs = xsh[srcs16[e]];
#pragma unroll
      for (int h = 0; h < H_; ++h){
        float v = fmaf(cs[h], xs, cdxn[h]);
        v = fmaxf(v, 0.2f * v);
        float d = v - mh[h];
        float ed = ex2na(d);
        bool nm = d > 0.f;
        float corr = nm ? ed : 1.f;
        float p    = nm ? 1.f : ed;
        mh[h] = fmaxf(mh[h], v);
        den[h] = fmaf(den[h], corr, p);
        num[h] = fmaf(num[h], corr, p * xs);
      }
    }
  }

  float o = 0.f;
#pragma unroll
  for (int h = 0; h < H_; ++h) o += wv[h] * num[h] * __builtin_amdgcn_rcpf(den[h]);
  o = o * 0.125f + gbias[0];
  o = (o - bnm[0]) / sqrtf(bnv[0] + EPS_) * bng[0] + bnb[0];
  o = o / (1.0f + __expf(-o));
  float res = o + xres[n];

  if (MODE == 2){
    float m2 = act ? res * dv[nl] : -INFINITY;
#pragma unroll
    for (int s = 32; s >= 1; s >>= 1) m2 = fmaxf(m2, __shfl_xor(m2, s, 64));
    int wv2 = tid >> 6, l2 = tid & 63;
    if (l2 == 0) sred[wv2] = m2;
    __syncthreads();
    if (tid == 0){
      float p = sred[0];
#pragma unroll
      for (int i2 = 1; i2 < 10; ++i2) p = fmaxf(p, sred[i2]);
      pmax[blockIdx.x] = p;
    }
  } else {
    if (act) xout[n] = res;
  }
}

__global__ void k_pool2(const float* __restrict__ pmax, const float* __restrict__ lw,
                        const float* __restrict__ lb, float* __restrict__ out){
  int b = blockIdx.x, l = threadIdx.x;
  float m = (l < GB_) ? pmax[b * GB_ + l] : -INFINITY;
#pragma unroll
  for (int s = 32; s >= 1; s >>= 1) m = fmaxf(m, __shfl_xor(m, s, 64));
  if (l == 0){
    float o = m * lw[0] + lb[0];
    out[b] = (o > 0.f) ? o : 0.f;
  }
}

// ---------------- launch ----------------
extern "C" void kernel_launch(void* const* d_in, const int* in_sizes, int n_in,
                              void* d_out, int out_size, void* d_ws, size_t ws_size,
                              hipStream_t stream){
  const float* x     = (const float*)d_in[0];
  const int*   ei    = (const int*)d_in[1];
  const float* W     = (const float*)d_in[3];
  const float* dv    = (const float*)d_in[4];
  const float* gw    = (const float*)d_in[5];
  const float* asrc  = (const float*)d_in[6];
  const float* adst  = (const float*)d_in[7];
  const float* gbias = (const float*)d_in[8];
  const float* bng   = (const float*)d_in[9];
  const float* bnb   = (const float*)d_in[10];
  const float* bnm   = (const float*)d_in[11];
  const float* bnv   = (const float*)d_in[12];
  const float* lw    = (const float*)d_in[13];
  const float* lb    = (const float*)d_in[14];
  float* out = (float*)d_out;

  char* ws = (char*)d_ws;
  int*            offs   = (int*)           (ws + 0);         // NT_+1 ints
  unsigned short* srcs16 = (unsigned short*)(ws + 640256);    // E_ u16 (10.24 MB)
  int*            cnt    = (int*)           (ws + 10880256);  // EB_*NB_ ints
  int*            gscan  = (int*)           (ws + 12160256);  // EB_*NB_ ints
  unsigned*       ebuf   = (unsigned*)      (ws + 21120256);  // E_ u32
  float*          ypart  = (float*)         (ws + 21120256);  // aliases ebuf
  float*          y      = (float*)         (ws + 41600256);  // NT_ f32 (x_res)
  float*          x0     = (float*)         (ws + 42240256);  // NT_ f32
  float*          x1     = (float*)         (ws + 42880256);  // NT_ f32
  int*            bsum   = (int*)           (ws + 43520256);  // NB_ ints
  int*            boff   = (int*)           (ws + 43522816);  // NB_+1 ints
  float*          pmax   = (float*)         (ws + 43525376);  // B_*GB_ f32
  float*          stats  = (float*)         (ws + 43527936);  // 8 f32
  float*          spart  = (float*)         (ws + 43527968);  // 625*3 f32
  if (ws_size < (size_t)43535500) return;

  const int* esrc = ei;
  const int* edst = ei + E_;

  k_hist  <<<EB_, ATH_, 0, stream>>>(edst, cnt);
  k_sumb  <<<NB_, 512, 0, stream>>>(cnt, bsum);
  k_scanb <<<1, 640, 0, stream>>>(bsum, boff);
  k_scanc <<<NB_, 512, 0, stream>>>(cnt, boff, gscan);
  k_append<<<EB_, ATH_, 0, stream>>>(esrc, edst, cnt, gscan, ebuf);
  k_bcsr  <<<NB_, 512, 0, stream>>>(boff, ebuf, offs, srcs16);
  k_perm  <<<T_ * B_ * JC_, 512, 0, stream>>>(W, x, ypart);
  k_ycomb <<<625, 256, 0, stream>>>(ypart, y, spart);
  k_stat2 <<<1, 256, 0, stream>>>(spart, stats);
  k_gat<1><<<B_ * GB_, GTH_, 0, stream>>>(y,  y, offs, srcs16, gw, asrc, adst, gbias, bng, bnb, bnm, bnv, stats, dv, x1, pmax);
  k_gat<0><<<B_ * GB_, GTH_, 0, stream>>>(x1, y, offs, srcs16, gw, asrc, adst, gbias, bng, bnb, bnm, bnv, stats, dv, x0, pmax);
  k_gat<0><<<B_ * GB_, GTH_, 0, stream>>>(x0, y, offs, srcs16, gw, asrc, adst, gbias, bng, bnb, bnm, bnv, stats, dv, x1, pmax);
  k_gat<2><<<B_ * GB_, GTH_, 0, stream>>>(x1, y, offs, srcs16, gw, asrc, adst, gbias, bng, bnb, bnm, bnv, stats, dv, x0, pmax);
  k_pool2 <<<B_, 64, 0, stream>>>(pmax, lw, lb, out);
}

// Round 16
// 293.092 us; speedup vs baseline: 1.0108x; 1.0108x over previous
//
#include <hip/hip_runtime.h>
#include <stdint.h>
#include <math.h>

#define B_   16
#define T_   50
#define C_   200
#define N_   10000      // T_*C_
#define NT_  160000     // B_*N_
#define H_   8
#define E_   5120000
#define EPS_ 1e-5f
#define NB_  625        // CSR buckets: dst>>8
#define EB_  512        // edge blocks for hist/append
#define EPB_ 10000      // edges per block (E_/EB_)
#define ATH_ 1024       // threads for hist/append
#define GB_  16         // chunks per graph (gat) -> grid = 256 = 1 block/CU
#define GC_  625        // nodes per chunk (N_/GB_)
#define GTH_ 640        // threads for gat (10 waves, 625 active)
#define JC_  5          // column chunks per perm tile
#define JW_  40         // columns per chunk
#define ROWP_ 41        // padded LDS row stride
#define BCAP_ 10240     // k_bcsr LDS staging capacity
#define LOG2E_ 1.44269504088896340736f

// native single-instruction transcendentals
__device__ __forceinline__ float ex2(float x){
  float r; asm("v_exp_f32 %0, %1" : "=v"(r) : "v"(x)); return r;
}
__device__ __forceinline__ float ex2na(float x){
  float r; asm("v_exp_f32 %0, -abs(%1)" : "=v"(r) : "v"(x)); return r;
}
__device__ __forceinline__ float lg2(float x){
  float r; asm("v_log_f32 %0, %1" : "=v"(r) : "v"(x)); return r;
}

// wave-64 inclusive scan (shfl)
__device__ __forceinline__ int wscan_incl(int v, int lane){
#pragma unroll
  for (int d = 1; d < 64; d <<= 1){
    int t = __shfl_up(v, d, 64);
    if (lane >= d) v += t;
  }
  return v;
}

// ---------------- Threefry-2x32 (JAX) ----------------
struct TF2C { unsigned a, b; };
constexpr unsigned rotl32c(unsigned v, int r){ return (v << r) | (v >> (32 - r)); }
constexpr TF2C tf_const(unsigned k0, unsigned k1, unsigned x0, unsigned x1){
  unsigned ks2 = k0 ^ k1 ^ 0x1BD11BDAu;
  unsigned ks[3] = {k0, k1, ks2};
  x0 += k0; x1 += k1;
  const int RA[4] = {13, 15, 26, 6};
  const int RB[4] = {17, 29, 16, 24};
  for (int g = 0; g < 5; ++g){
    for (int r = 0; r < 4; ++r){
      int rr = (g & 1) ? RB[r] : RA[r];
      x0 += x1; x1 = rotl32c(x1, rr); x1 ^= x0;
    }
    x0 += ks[(g + 1) % 3];
    x1 += ks[(g + 2) % 3] + (unsigned)(g + 1);
  }
  return TF2C{x0, x1};
}
constexpr TF2C KG = tf_const(0u, 42u, 0u, 0u);
constexpr TF2C KN = tf_const(0u, 42u, 0u, 1u);

#define ROTL_(x, r) __builtin_amdgcn_alignbit((x), (x), 32 - (r))

__device__ __forceinline__ void tf2(unsigned k0, unsigned k1, unsigned x0, unsigned x1,
                                    unsigned &o0, unsigned &o1){
  unsigned ks2 = k0 ^ k1 ^ 0x1BD11BDAu;
  x0 += k0; x1 += k1;
#define TFR_(R) { x0 += x1; x1 = ROTL_(x1, R); x1 ^= x0; }
  TFR_(13) TFR_(15) TFR_(26) TFR_(6)  x0 += k1;  x1 += ks2 + 1u;
  TFR_(17) TFR_(29) TFR_(16) TFR_(24) x0 += ks2; x1 += k0 + 2u;
  TFR_(13) TFR_(15) TFR_(26) TFR_(6)  x0 += k0;  x1 += k1 + 3u;
  TFR_(17) TFR_(29) TFR_(16) TFR_(24) x0 += k1;  x1 += ks2 + 4u;
  TFR_(13) TFR_(15) TFR_(26) TFR_(6)  x0 += ks2; x1 += k0 + 5u;
#undef TFR_
  o0 = x0; o1 = x1;
}
__device__ __forceinline__ unsigned rbits(unsigned ka, unsigned kb, unsigned m){
  unsigned a, b; tf2(ka, kb, 0u, m, a, b); return a ^ b;
}

__device__ __forceinline__ float erfinv_xla(float x){
  float w = -log1pf(-x * x);
  float p;
  if (w < 5.0f){
    w = w - 2.5f;
    p = 2.81022636e-08f;
    p = fmaf(p, w, 3.43273939e-07f);
    p = fmaf(p, w, -3.5233877e-06f);
    p = fmaf(p, w, -4.39150654e-06f);
    p = fmaf(p, w, 0.00021858087f);
    p = fmaf(p, w, -0.00125372503f);
    p = fmaf(p, w, -0.00417768164f);
    p = fmaf(p, w, 0.246640727f);
    p = fmaf(p, w, 1.50140941f);
  } else {
    w = sqrtf(w) - 3.0f;
    p = -0.000200214257f;
    p = fmaf(p, w, 0.000100950558f);
    p = fmaf(p, w, 0.00134934322f);
    p = fmaf(p, w, -0.00367342844f);
    p = fmaf(p, w, 0.00573950773f);
    p = fmaf(p, w, -0.0076224613f);
    p = fmaf(p, w, 0.00943887047f);
    p = fmaf(p, w, 1.00167406f);
    p = fmaf(p, w, 2.83297682f);
  }
  return p * x;
}

// ---------------- CSR build (proven multi-kernel path) ----------------
__global__ __launch_bounds__(ATH_)
void k_hist(const int* __restrict__ dst, int* __restrict__ cnt){
  __shared__ int h[NB_];
  int tid = threadIdx.x, blk = blockIdx.x;
  for (int i = tid; i < NB_; i += ATH_) h[i] = 0;
  __syncthreads();
  int e0 = blk * EPB_;
  for (int i = tid; i < EPB_; i += ATH_)
    atomicAdd(&h[dst[e0 + i] >> 8], 1);
  __syncthreads();
  for (int i = tid; i < NB_; i += ATH_) cnt[blk * NB_ + i] = h[i];
}

__global__ __launch_bounds__(512)
void k_sumb(const int* __restrict__ cnt, int* __restrict__ bsum){
  __shared__ int sred[8];
  int b = blockIdx.x, tid = threadIdx.x;
  int v = cnt[tid * NB_ + b];
#pragma unroll
  for (int s = 32; s >= 1; s >>= 1) v += __shfl_xor(v, s, 64);
  int w = tid >> 6, l = tid & 63;
  if (l == 0) sred[w] = v;
  __syncthreads();
  if (tid == 0){
    int t = 0;
#pragma unroll
    for (int i = 0; i < 8; ++i) t += sred[i];
    bsum[b] = t;
  }
}

__global__ __launch_bounds__(640)
void k_scanb(const int* __restrict__ bsum, int* __restrict__ boff){
  __shared__ int wsum[16];
  int tid = threadIdx.x, lane = tid & 63, wid = tid >> 6;   // 10 waves
  int v = (tid < NB_) ? bsum[tid] : 0;
  int inc = wscan_incl(v, lane);
  if (lane == 63) wsum[wid] = inc;
  __syncthreads();
  if (wid == 0){
    int wv = (lane < 10) ? wsum[lane] : 0;
    int wi = wscan_incl(wv, lane);
    if (lane < 10) wsum[lane] = wi - wv;
  }
  __syncthreads();
  if (tid < NB_) boff[tid] = inc - v + wsum[wid];
  if (tid == 0) boff[NB_] = E_;
}

__global__ __launch_bounds__(512)
void k_scanc(const int* __restrict__ cnt, const int* __restrict__ boff,
             int* __restrict__ gscan){
  __shared__ int wsum[8];
  int b = blockIdx.x, tid = threadIdx.x, lane = tid & 63, wid = tid >> 6;
  int v = cnt[tid * NB_ + b];
  int inc = wscan_incl(v, lane);
  if (lane == 63) wsum[wid] = inc;
  __syncthreads();
  int wp = 0;
#pragma unroll
  for (int k = 0; k < 8; ++k) wp += (k < wid) ? wsum[k] : 0;
  gscan[tid * NB_ + b] = boff[b] + inc - v + wp;
}

__global__ __launch_bounds__(ATH_)
void k_append(const int* __restrict__ src, const int* __restrict__ dst,
              const int* __restrict__ cnt, const int* __restrict__ gscan,
              unsigned* __restrict__ ebuf){
  __shared__ unsigned esh[EPB_];     // 40 KB staging
  __shared__ int loff[NB_ + 1];
  __shared__ int cur[NB_];
  __shared__ int wsum[16];
  int tid = threadIdx.x, blk = blockIdx.x;
  int lane = tid & 63, wid = tid >> 6;
  int e0 = blk * EPB_;
  for (int i = tid; i < NB_; i += ATH_) cur[i] = 0;
  int hv = (tid < NB_) ? cnt[blk * NB_ + tid] : 0;
  int inc = wscan_incl(hv, lane);
  if (lane == 63 && wid < 10) wsum[wid] = inc;
  __syncthreads();
  if (wid == 0){
    int wv = (lane < 10) ? wsum[lane] : 0;
    int wi = wscan_incl(wv, lane);
    if (lane < 10) wsum[lane] = wi - wv;
  }
  __syncthreads();
  if (tid < NB_) loff[tid] = inc - hv + wsum[wid];
  if (tid == 0) loff[NB_] = EPB_;
  __syncthreads();
  for (int i = tid; i < EPB_; i += ATH_){
    int e = e0 + i;
    int d = dst[e];
    int b = d >> 8;
    int p = loff[b] + atomicAdd(&cur[b], 1);
    esh[p] = ((unsigned)src[e] << 8) | (unsigned)(d & 255);
  }
  __syncthreads();
  for (int b = wid; b < NB_; b += ATH_ / 64){
    int lo = loff[b], len = loff[b + 1] - lo;
    int gb0 = gscan[blk * NB_ + b];
    for (int p = lane; p < len; p += 64)
      ebuf[gb0 + p] = esh[lo + p];
  }
}

__global__ __launch_bounds__(512)
void k_bcsr(const int* __restrict__ boff, const unsigned* __restrict__ ebuf,
            int* __restrict__ offs, unsigned short* __restrict__ srcs16){
  __shared__ unsigned esh[BCAP_];    // 40 KB
  __shared__ int cnt[256];
  __shared__ int cur[256];
  __shared__ int wsum[4];
  int b = blockIdx.x, tid = threadIdx.x, lane = tid & 63, wid = tid >> 6;
  int e0 = boff[b], e1 = boff[b + 1];
  int len = e1 - e0;
  int base_node = b * 256;
  int offA = (base_node / N_) * N_;
  int boundary = offA + N_;
  bool staged = (len <= BCAP_);
  if (tid < 256) cnt[tid] = 0;
  __syncthreads();
  if (staged){
    for (int e = tid; e < len; e += 512){
      unsigned pk = ebuf[e0 + e];
      esh[e] = pk;
      atomicAdd(&cnt[pk & 255u], 1);
    }
  } else {
    for (int e = tid; e < len; e += 512)
      atomicAdd(&cnt[ebuf[e0 + e] & 255u], 1);
  }
  __syncthreads();
  int v = (tid < 256) ? cnt[tid] : 0;
  int inc = wscan_incl(v, lane);
  if (lane == 63 && wid < 4) wsum[wid] = inc;
  __syncthreads();
  int wp = 0;
#pragma unroll
  for (int k = 0; k < 4; ++k) wp += (k < wid) ? wsum[k] : 0;
  int excl = inc - v + wp;
  if (tid < 256){ offs[base_node + tid] = e0 + excl; cur[tid] = excl; }
  __syncthreads();
  if (staged){
    for (int e = tid; e < len; e += 512){
      unsigned pk = esh[e];
      int dl = (int)(pk & 255u);
      int goff = (base_node + dl >= boundary) ? boundary : offA;
      int pos = e0 + atomicAdd(&cur[dl], 1);
      srcs16[pos] = (unsigned short)((int)(pk >> 8) - goff);
    }
  } else {
    for (int e = tid; e < len; e += 512){
      unsigned pk = ebuf[e0 + e];
      int dl = (int)(pk & 255u);
      int goff = (base_node + dl >= boundary) ? boundary : offA;
      int pos = e0 + atomicAdd(&cur[dl], 1);
      srcs16[pos] = (unsigned short)((int)(pk >> 8) - goff);
    }
  }
  if (b == 0 && tid == 0) offs[NT_] = E_;
}

// ---------------- permutation layer ----------------
__global__ __launch_bounds__(512, 8)
void k_perm(const float* __restrict__ W, const float* __restrict__ x,
            float* __restrict__ ypart){
  __shared__ float ez[C_ * ROWP_];          // 32.8 KB
  __shared__ float Ssh[JW_];
  __shared__ float rs[JW_];

  const int bid = blockIdx.x;               // tb*JC_ + jc
  const int tb = bid / JC_;
  const int jc = bid - tb * JC_;
  const int t = tb / B_;
  const int b = tb - t * B_;
  const int j0 = jc * JW_;
  const int xoff = (b * T_ + t) * C_;
  const int tid = threadIdx.x;
  const int w = tid >> 6, l = tid & 63;

  {
    int i  = tid / 10;                       // quad row (10 quads per row)
    int jq = tid - i * 10;                   // quad col
    unsigned m = (unsigned)(tb * (C_ * C_) + i * C_ + j0 + 4 * jq);
    int la = i * ROWP_ + 4 * jq;
    int niter = (2000 - tid + 511) >> 9;     // 3 or 4 quads per thread
    for (int it = 0; it < niter; ++it){
      float4 w4 = *reinterpret_cast<const float4*>(W + m);   // m % 4 == 0
      unsigned bb0 = rbits(KG.a, KG.b, m);
      unsigned bb1 = rbits(KG.a, KG.b, m + 1u);
      unsigned bb2 = rbits(KG.a, KG.b, m + 2u);
      unsigned bb3 = rbits(KG.a, KG.b, m + 3u);
      unsigned bbv[4] = {bb0, bb1, bb2, bb3};
      float wvv[4] = {w4.x, w4.y, w4.z, w4.w};
#pragma unroll
      for (int k = 0; k < 4; ++k){
        unsigned bits = bbv[k];
        float fc = (float)(bits >> 9);                 // exact, = f * 2^23
        float u  = fmaf(fc, 0x1p-23f, 1e-10f);         // uniform(1e-10,1)
        float tl = lg2(u) * -0.69314718056f;           // -ln(u)
        float d  = fmaf(-fc, 0x1p-23f, 1.0f);          // exact 1-f
        float p  = 0.25f;                              // -log(1-d) = d*poly(d)
        p = fmaf(p, d, 0.33333333f);
        p = fmaf(p, d, 0.5f);
        p = fmaf(p, d, 1.0f);
        float tneg = (bits >= 0xFC000000u) ? d * p : tl;   // f >= 1-2^-6 -> poly
        ez[la + k] = ex2(wvv[k] * LOG2E_) * __builtin_amdgcn_rcpf(tneg);
      }
      jq += 2;
      int wrap = jq >= 10;
      jq = wrap ? jq - 10 : jq;
      m  += wrap ? 10368u : 10208u;
      la += wrap ? 2100 : 2099;
    }
  }
  __syncthreads();

#pragma unroll
  for (int q = 0; q < 5; ++q){
    int jj = w * 5 + q;
    float s = ez[l * ROWP_ + jj] + ez[(l + 64) * ROWP_ + jj] + ez[(l + 128) * ROWP_ + jj]
            + ((l < 8) ? ez[(l + 192) * ROWP_ + jj] : 0.f);
#pragma unroll
    for (int sh = 32; sh >= 1; sh >>= 1) s += __shfl_xor(s, sh, 64);
    if (l == 0) Ssh[jj] = s;
  }
  __syncthreads();
  if (tid < JW_) rs[tid] = x[xoff + j0 + tid] / Ssh[tid];
  __syncthreads();

  if (tid < C_){
    float acc = 0.f;
#pragma unroll 8
    for (int jj = 0; jj < JW_; ++jj)
      acc = fmaf(ez[tid * ROWP_ + jj], rs[jj], acc);
    ypart[jc * NT_ + xoff + tid] = acc;
  }
}

// combine 5 column-chunk partials -> y, plus nonzero stats partials
__global__ __launch_bounds__(256)
void k_ycomb(const float* __restrict__ ypart, float* __restrict__ y,
             float* __restrict__ spart){
  __shared__ float sred[12];
  int n = blockIdx.x * 256 + threadIdx.x;
  float v = 0.f;
#pragma unroll
  for (int jc = 0; jc < JC_; ++jc) v += ypart[jc * NT_ + n];
  y[n] = v;
  float s = 0.f, c = 0.f, q = 0.f;
  if (v != 0.f){ s = v; c = 1.f; q = v * v; }
#pragma unroll
  for (int sh = 32; sh >= 1; sh >>= 1){
    s += __shfl_xor(s, sh, 64);
    c += __shfl_xor(c, sh, 64);
    q += __shfl_xor(q, sh, 64);
  }
  int w = threadIdx.x >> 6, l = threadIdx.x & 63;
  if (l == 0){ sred[w] = s; sred[4 + w] = c; sred[8 + w] = q; }
  __syncthreads();
  if (threadIdx.x == 0){
    spart[blockIdx.x * 3 + 0] = sred[0] + sred[1] + sred[2] + sred[3];
    spart[blockIdx.x * 3 + 1] = sred[4] + sred[5] + sred[6] + sred[7];
    spart[blockIdx.x * 3 + 2] = sred[8] + sred[9] + sred[10] + sred[11];
  }
}

// ---------------- fused GAT pass ----------------
// MODE 0: normal.  MODE 1: inline spart-reduce + noise injection (pass 1).
// MODE 2: fused mask + global-max-pool output, no xout write (pass 4).
template<int MODE>
__global__ __launch_bounds__(GTH_)
void k_gat(const float* __restrict__ xin, const float* __restrict__ xres,
           const int* __restrict__ offs, const unsigned short* __restrict__ srcs16,
           const float* __restrict__ gw, const float* __restrict__ asrc,
           const float* __restrict__ adst, const float* __restrict__ gbias,
           const float* __restrict__ bng, const float* __restrict__ bnb,
           const float* __restrict__ bnm, const float* __restrict__ bnv,
           const float* __restrict__ spart, const float* __restrict__ dv,
           float* __restrict__ xout, float* __restrict__ pmax){
  __shared__ float xsh[N_];                      // whole graph: 40 KB
  __shared__ float sred3[32];
  int g = blockIdx.x / GB_, c = blockIdx.x - g * GB_;
  int tid = threadIdx.x;
  if (MODE == 1){
    // redundant per-block reduction of spart -> scale (deterministic)
    float s = 0.f, cc = 0.f, q = 0.f;
    for (int i = tid; i < 625; i += GTH_){
      s += spart[i * 3 + 0]; cc += spart[i * 3 + 1]; q += spart[i * 3 + 2];
    }
#pragma unroll
    for (int sh = 32; sh >= 1; sh >>= 1){
      s += __shfl_xor(s, sh, 64);
      cc += __shfl_xor(cc, sh, 64);
      q += __shfl_xor(q, sh, 64);
    }
    int wv2 = tid >> 6, l2 = tid & 63;
    if (l2 == 0){ sred3[wv2] = s; sred3[10 + wv2] = cc; sred3[20 + wv2] = q; }
    __syncthreads();
    float S = 0.f, C2 = 0.f, Q = 0.f;
#pragma unroll
    for (int k = 0; k < 10; ++k){ S += sred3[k]; C2 += sred3[10 + k]; Q += sred3[20 + k]; }
    float scale = sqrtf((Q - S * S / C2) / (C2 - 1.f)) * 0.01f;
    for (int i = tid; i < N_; i += GTH_){
      float v = xin[g * N_ + i];
      if (v == 0.0f){
        unsigned bits = rbits(KN.a, KN.b, (unsigned)(g * N_ + i));
        float f = __uint_as_float((bits >> 9) | 0x3f800000u) - 1.0f;
        float u = fmaf(f, 2.0f, -0.99999994f);
        u = fmaxf(-0.99999994f, u);
        v = scale * 1.41421356237f * erfinv_xla(u);
      }
      xsh[i] = v;
    }
  } else {
    const float4* xv = (const float4*)(xin + g * N_);
    for (int i = tid; i < N_ / 4; i += GTH_) ((float4*)xsh)[i] = xv[i];
  }
  __syncthreads();

  bool act = tid < GC_;
  int nl = c * GC_ + (act ? tid : 0);
  int n = g * N_ + nl;
  float xn = xsh[nl];

  float cs[H_], cdxn[H_], wv[H_];
#pragma unroll
  for (int h = 0; h < H_; ++h){
    wv[h] = gw[h];
    cs[h] = wv[h] * asrc[h] * LOG2E_;
    cdxn[h] = wv[h] * adst[h] * xn * LOG2E_;
  }
  float mh[H_], den[H_], num[H_];
#pragma unroll
  for (int h = 0; h < H_; ++h){
    float v = cs[h] * xn + cdxn[h];
    v = fmaxf(v, 0.2f * v);
    mh[h] = v; den[h] = 1.f; num[h] = xn;
  }
  int e0 = offs[n], e1 = act ? offs[n + 1] : e0;

  int e = e0;
  if ((e < e1) && (e & 1)){                 // peel to align pair loads
    float xs = xsh[srcs16[e]];
#pragma unroll
    for (int h = 0; h < H_; ++h){
      float v = fmaf(cs[h], xs, cdxn[h]);
      v = fmaxf(v, 0.2f * v);
      float d = v - mh[h];
      float ed = ex2na(d);
      bool nm = d > 0.f;
      float corr = nm ? ed : 1.f;
      float p    = nm ? 1.f : ed;
      mh[h] = fmaxf(mh[h], v);
      den[h] = fmaf(den[h], corr, p);
      num[h] = fmaf(num[h], corr, p * xs);
    }
    ++e;
  }
  for (; e + 1 < e1; e += 2){
    unsigned pr = *reinterpret_cast<const unsigned*>(srcs16 + e);  // aligned
    float xa = xsh[pr & 0xFFFFu];
    float xb = xsh[pr >> 16];
#pragma unroll
    for (int h = 0; h < H_; ++h){
      float va = fmaf(cs[h], xa, cdxn[h]);  va = fmaxf(va, 0.2f * va);
      float vb = fmaf(cs[h], xb, cdxn[h]);  vb = fmaxf(vb, 0.2f * vb);
      float m2 = fmaxf(va, vb);
      float ed2 = ex2na(va - vb);
      bool bmx = vb > va;
      float xmx = bmx ? xb : xa;
      float xmn = bmx ? xa : xb;
      float den2 = 1.0f + ed2;
      float num2 = fmaf(ed2, xmn, xmx);
      float d = m2 - mh[h];
      float ed = ex2na(d);
      bool nm = d > 0.f;
      float corr = nm ? ed : 1.f;
      float p    = nm ? 1.f : ed;
      mh[h] = fmaxf(mh[h], m2);
      den[h] = fmaf(den[h], corr, p * den2);
      num[h] = fmaf(num[h], corr, p * num2);
    }
  }
  if (e < e1){                              // tail edge
    float xs = xsh[srcs16[e]];
#pragma unroll
    for (int h = 0; h < H_; ++h){
      float v = fmaf(cs[h], xs, cdxn[h]);
      v = fmaxf(v, 0.2f * v);
      float d = v - mh[h];
      float ed = ex2na(d);
      bool nm = d > 0.f;
      float corr = nm ? ed : 1.f;
      float p    = nm ? 1.f : ed;
      mh[h] = fmaxf(mh[h], v);
      den[h] = fmaf(den[h], corr, p);
      num[h] = fmaf(num[h], corr, p * xs);
    }
  }

  float o = 0.f;
#pragma unroll
  for (int h = 0; h < H_; ++h) o += wv[h] * num[h] * __builtin_amdgcn_rcpf(den[h]);
  o = o * 0.125f + gbias[0];
  o = (o - bnm[0]) / sqrtf(bnv[0] + EPS_) * bng[0] + bnb[0];
  o = o / (1.0f + __expf(-o));
  float res = o + xres[n];

  if (MODE == 2){
    float m2 = act ? res * dv[nl] : -INFINITY;
#pragma unroll
    for (int s = 32; s >= 1; s >>= 1) m2 = fmaxf(m2, __shfl_xor(m2, s, 64));
    int wv2 = tid >> 6, l2 = tid & 63;
    if (l2 == 0) sred3[wv2] = m2;
    __syncthreads();
    if (tid == 0){
      float p = sred3[0];
#pragma unroll
      for (int i2 = 1; i2 < 10; ++i2) p = fmaxf(p, sred3[i2]);
      pmax[blockIdx.x] = p;
    }
  } else {
    if (act) xout[n] = res;
  }
}

__global__ void k_pool2(const float* __restrict__ pmax, const float* __restrict__ lw,
                        const float* __restrict__ lb, float* __restrict__ out){
  int b = blockIdx.x, l = threadIdx.x;
  float m = (l < GB_) ? pmax[b * GB_ + l] : -INFINITY;
#pragma unroll
  for (int s = 32; s >= 1; s >>= 1) m = fmaxf(m, __shfl_xor(m, s, 64));
  if (l == 0){
    float o = m * lw[0] + lb[0];
    out[b] = (o > 0.f) ? o : 0.f;
  }
}

// ---------------- launch ----------------
extern "C" void kernel_launch(void* const* d_in, const int* in_sizes, int n_in,
                              void* d_out, int out_size, void* d_ws, size_t ws_size,
                              hipStream_t stream){
  const float* x     = (const float*)d_in[0];
  const int*   ei    = (const int*)d_in[1];
  const float* W     = (const float*)d_in[3];
  const float* dv    = (const float*)d_in[4];
  const float* gw    = (const float*)d_in[5];
  const float* asrc  = (const float*)d_in[6];
  const float* adst  = (const float*)d_in[7];
  const float* gbias = (const float*)d_in[8];
  const float* bng   = (const float*)d_in[9];
  const float* bnb   = (const float*)d_in[10];
  const float* bnm   = (const float*)d_in[11];
  const float* bnv   = (const float*)d_in[12];
  const float* lw    = (const float*)d_in[13];
  const float* lb    = (const float*)d_in[14];
  float* out = (float*)d_out;

  char* ws = (char*)d_ws;
  int*            offs   = (int*)           (ws + 0);         // NT_+1 ints
  unsigned short* srcs16 = (unsigned short*)(ws + 640256);    // E_ u16
  int*            cnt    = (int*)           (ws + 10880256);  // EB_*NB_ ints
  int*            gscan  = (int*)           (ws + 12160256);  // EB_*NB_ ints
  unsigned*       ebuf   = (unsigned*)      (ws + 21120256);  // E_ u32
  float*          ypart  = (float*)         (ws + 21120256);  // aliases ebuf
  float*          y      = (float*)         (ws + 41600256);  // NT_ f32 (x_res)
  float*          x0     = (float*)         (ws + 42240256);  // NT_ f32
  float*          x1     = (float*)         (ws + 42880256);  // NT_ f32
  int*            bsum   = (int*)           (ws + 43520256);  // NB_ ints
  int*            boff   = (int*)           (ws + 43522816);  // NB_+1 ints
  float*          pmax   = (float*)         (ws + 43525376);  // B_*GB_ f32
  float*          spart  = (float*)         (ws + 43527968);  // 625*3 f32
  if (ws_size < (size_t)43535500) return;

  const int* esrc = ei;
  const int* edst = ei + E_;

  k_hist  <<<EB_, ATH_, 0, stream>>>(edst, cnt);
  k_sumb  <<<NB_, 512, 0, stream>>>(cnt, bsum);
  k_scanb <<<1, 640, 0, stream>>>(bsum, boff);
  k_scanc <<<NB_, 512, 0, stream>>>(cnt, boff, gscan);
  k_append<<<EB_, ATH_, 0, stream>>>(esrc, edst, cnt, gscan, ebuf);
  k_bcsr  <<<NB_, 512, 0, stream>>>(boff, ebuf, offs, srcs16);
  k_perm  <<<T_ * B_ * JC_, 512, 0, stream>>>(W, x, ypart);
  k_ycomb <<<625, 256, 0, stream>>>(ypart, y, spart);
  k_gat<1><<<B_ * GB_, GTH_, 0, stream>>>(y,  y, offs, srcs16, gw, asrc, adst, gbias, bng, bnb, bnm, bnv, spart, dv, x1, pmax);
  k_gat<0><<<B_ * GB_, GTH_, 0, stream>>>(x1, y, offs, srcs16, gw, asrc, adst, gbias, bng, bnb, bnm, bnv, spart, dv, x0, pmax);
  k_gat<0><<<B_ * GB_, GTH_, 0, stream>>>(x0, y, offs, srcs16, gw, asrc, adst, gbias, bng, bnb, bnm, bnv, spart, dv, x1, pmax);
  k_gat<2><<<B_ * GB_, GTH_, 0, stream>>>(x1, y, offs, srcs16, gw, asrc, adst, gbias, bng, bnb, bnm, bnv, spart, dv, x0, pmax);
  k_pool2 <<<B_, 64, 0, stream>>>(pmax, lw, lb, out);
}